// Round 17
// baseline (255.262 us; speedup 1.0000x reference)
//
#include <hip/hip_runtime.h>
#include <cstdint>
#include <cstddef>

// GNNDi: B=2, V=256, H=128, L=3, GroupNorm32 head. e stored [b][i][j][h] bf16.
// Weights pre-packed in MFMA fragment order: WF[(nt*4+kst)*64 + lane] (16B/lane),
// value = W[k][n], n = nt*16 + (lane&15), k = kst*32 + (lane>>4)*8 + e.

#define EPSV 1e-5f

typedef __attribute__((ext_vector_type(8))) short short8v;  // 8 bf16
typedef __attribute__((ext_vector_type(4))) float f32x4;

__device__ __forceinline__ float sigmoidf_(float x) { return 1.f / (1.f + __expf(-x)); }

__device__ __forceinline__ unsigned short f2bf(float x) {
    unsigned int u = __float_as_uint(x);
    unsigned int r = u + 0x7FFFu + ((u >> 16) & 1u);   // RNE
    return (unsigned short)(r >> 16);
}
__device__ __forceinline__ float bf2f(unsigned short u) {
    return __uint_as_float(((unsigned int)u) << 16);
}
// packed f32x2 -> bf16x2 (RNE), lo=a, hi=b
__device__ __forceinline__ unsigned int cvtpk(float a, float b) {
    unsigned int r;
    asm("v_cvt_pk_bf16_f32 %0, %1, %2" : "=v"(r) : "v"(a), "v"(b));
    return r;
}
#define SWZ(row, cb) ((cb) ^ (((row) & 7) << 4))

// ---------------- K_prep: node embed + aggB zero (blocks 0..511), wcomb (512), weight frag-pack (513..518)
__global__ void k_prep(const int* __restrict__ x, const float* __restrict__ emb,
                       const float* __restrict__ W_node, const float* __restrict__ b_node,
                       float* __restrict__ h, float* __restrict__ aggB,
                       const float* __restrict__ W_ea, const float* __restrict__ b_ea,
                       const float* __restrict__ W_ee, const float* __restrict__ b_ee,
                       float* __restrict__ Wcb, float* __restrict__ bcb,
                       const float* __restrict__ Wc, const float* __restrict__ PW,
                       unsigned short* __restrict__ WT)
{
    const int blk = blockIdx.x, t = threadIdx.x;
    if (blk < 512) {
        __shared__ float se[128];
        if (t < 128) { se[t] = emb[x[blk]*128 + t]; aggB[blk*128 + t] = 0.f; }
        __syncthreads();
        if (t < 128) {
            float acc = b_node[t];
            for (int k = 0; k < 128; ++k) acc = fmaf(se[k], W_node[k*128+t], acc);
            h[blk*128+t] = acc;
        }
    } else if (blk == 512) {
        if (t < 128) {
            float wc0=0,wc1=0,wc2=0,wc3=0,wc4=0,wc5=0,bv=0;
            for (int m = 0; m < 128; ++m) {
                float we = W_ee[m*128 + t];
                wc0 = fmaf(W_ea[0*128+m], we, wc0);
                wc1 = fmaf(W_ea[1*128+m], we, wc1);
                wc2 = fmaf(W_ea[2*128+m], we, wc2);
                wc3 = fmaf(W_ea[3*128+m], we, wc3);
                wc4 = fmaf(W_ea[4*128+m], we, wc4);
                wc5 = fmaf(W_ea[5*128+m], we, wc5);
                bv  = fmaf(b_ea[m], we, bv);
            }
            Wcb[0*128+t]=wc0; Wcb[1*128+t]=wc1; Wcb[2*128+t]=wc2;
            Wcb[3*128+t]=wc3; Wcb[4*128+t]=wc4; Wcb[5*128+t]=wc5;
            bcb[t] = bv + b_ee[t];
        }
    } else {
        const int m = blk - 513;            // 0..5 = layer*2 + (0:Wc, 1:plo_W)
        const int l = m >> 1;
        const float* src = (m & 1) ? (PW + (size_t)l*16384) : (Wc + (size_t)l*16384);
        unsigned short* dst = WT + (size_t)m*16384;
        for (int idx = t; idx < 16384; idx += 256) {
            const int frag  = idx >> 9;          // nt*4+kst
            const int lane  = (idx >> 3) & 63;   // g*16+lane16
            const int e2    = idx & 7;
            const int nt = frag >> 2, kst = frag & 3;
            const int lane16 = lane & 15, g = lane >> 4;
            const int n = nt*16 + lane16;
            const int k = kst*32 + g*8 + e2;
            dst[idx] = f2bf(src[k*128 + n]);     // frag-ordered
        }
    }
}

// ---------------- K3: fused h-update (from prev layer) + 4 h-GEMMs; zeroes aggB
// All outputs non-transposed [b*256+v][128].
__global__ void k_hgemm(float* __restrict__ h, float* __restrict__ Uh, float* __restrict__ aggB,
    const float* __restrict__ Wu_l, const float* __restrict__ bu_l,
    const float* __restrict__ Wv_l, const float* __restrict__ bv_l,
    const float* __restrict__ Wa_l, const float* __restrict__ ba_l,
    const float* __restrict__ Wb_l, const float* __restrict__ bb_l,
    float* __restrict__ Vh, float* __restrict__ Ah, float* __restrict__ Bh,
    const float* __restrict__ lnh_g, const float* __restrict__ lnh_b, int upd)
{
    __shared__ float sh[128];
    __shared__ float sred[4];
    int blk = blockIdx.x, t = threadIdx.x;
    float hv_ = h[blk*128 + t];
    if (upd) {
        float val = Uh[blk*128 + t] + aggB[blk*128 + t];
        aggB[blk*128 + t] = 0.f;
        float s = val, q = val*val;
        #pragma unroll
        for (int off = 32; off; off >>= 1) { s += __shfl_down(s, off); q += __shfl_down(q, off); }
        if ((t & 63) == 0) { sred[t>>6] = s; sred[2 + (t>>6)] = q; }
        __syncthreads();
        s = sred[0] + sred[1]; q = sred[2] + sred[3];
        float mean = s * (1.f/128.f);
        float var  = q * (1.f/128.f) - mean*mean;
        float nv = (val - mean) * rsqrtf(var + EPSV) * lnh_g[t] + lnh_b[t];
        hv_ += fmaxf(nv, 0.f);
        h[blk*128 + t] = hv_;
    }
    sh[t] = hv_;
    __syncthreads();
    float au=bu_l[t], av=bv_l[t], aa=ba_l[t], ab=bb_l[t];
    for (int k = 0; k < 128; ++k) {
        float hv = sh[k];
        au = fmaf(hv, Wu_l[k*128+t], au);
        av = fmaf(hv, Wv_l[k*128+t], av);
        aa = fmaf(hv, Wa_l[k*128+t], aa);
        ab = fmaf(hv, Wb_l[k*128+t], ab);
    }
    Uh[blk*128+t]=au; Bh[blk*128+t]=ab;
    Vh[blk*128+t]=av; Ah[blk*128+t]=aa;
}

// ---------------- K4: fused layer chunk. grid = 2048; 256 threads; each wave owns 16 rows x 128 cols.
// Weights read per-MFMA from frag-ordered global (coalesced 1KB wave-loads, L1/L2 resident).
// No LDS weight staging; Ua in dedicated wave-private LDS; main path barrier-free (EINIT: 1 drain barrier).
template<int EINIT, int DO_AGG, int DO_STATS>
__global__ __launch_bounds__(256) void k_layer(
    unsigned short* __restrict__ e,
    const unsigned short* __restrict__ WcF, const unsigned short* __restrict__ PWF,
    const float* __restrict__ bc_l,
    const float* __restrict__ Ah, const float* __restrict__ Bh,
    const float* __restrict__ Vh, const float* __restrict__ adj,
    const float* __restrict__ lne_g, const float* __restrict__ lne_b,
    const float* __restrict__ plo_g, const float* __restrict__ plo_b,
    const float* __restrict__ pbW_l,
    float* __restrict__ aggB,
    const float* __restrict__ Wcb, const float* __restrict__ bcb,
    float* __restrict__ ggsum, float* __restrict__ ggsq)
{
    __shared__ __align__(16) char sUa[16384];    // 4 waves x 4KB, wave-private Ua tile
    __shared__ float sRedA[512];
    __shared__ float sRedB[128];

    const int t = threadIdx.x;
    const int bi = blockIdx.x >> 2, chunk = blockIdx.x & 3;
    const int b = bi >> 8, i = bi & 255;
    const int w = t >> 6, lane = t & 63;
    const int lane16 = lane & 15, g = lane >> 4;
    const size_t rowbase = (size_t)bi * 32768;
    const int j0 = chunk*64 + w*16;
    char* sE = sUa + w*4096;

    // --- GEMM1 A-frags
    short8v a8[4];
    if (EINIT) {
        float am[6];
        const float* adjp = adj + (size_t)b*393216 + (size_t)i*256 + (j0 + lane16);
        #pragma unroll
        for (int m = 0; m < 6; ++m) am[m] = adjp[(size_t)m*65536];
        unsigned short* erow = &e[rowbase + (size_t)(j0 + lane16)*128];
        #pragma unroll
        for (int kst = 0; kst < 4; ++kst) {
            const int base = kst*32 + g*8;
            float4 v0 = *(const float4*)&bcb[base];
            float4 v1 = *(const float4*)&bcb[base+4];
            float vv[8] = {v0.x, v0.y, v0.z, v0.w, v1.x, v1.y, v1.z, v1.w};
            #pragma unroll
            for (int m = 0; m < 6; ++m) {
                const float4 w0 = *(const float4*)&Wcb[m*128 + base];
                const float4 w1 = *(const float4*)&Wcb[m*128 + base + 4];
                vv[0] = fmaf(am[m], w0.x, vv[0]); vv[1] = fmaf(am[m], w0.y, vv[1]);
                vv[2] = fmaf(am[m], w0.z, vv[2]); vv[3] = fmaf(am[m], w0.w, vv[3]);
                vv[4] = fmaf(am[m], w1.x, vv[4]); vv[5] = fmaf(am[m], w1.y, vv[5]);
                vv[6] = fmaf(am[m], w1.z, vv[6]); vv[7] = fmaf(am[m], w1.w, vv[7]);
            }
            short8v vfr;
            #pragma unroll
            for (int pr = 0; pr < 4; ++pr) {
                const unsigned int p = cvtpk(vv[pr*2], vv[pr*2+1]);
                vfr[pr*2]   = (short)(unsigned short)p;
                vfr[pr*2+1] = (short)(unsigned short)(p >> 16);
            }
            a8[kst] = vfr;
            *(short8v*)&erow[base] = vfr;   // materialize e0 (residual readback in epilogue)
        }
        __syncthreads();   // drain e0 stores before later readback (validated pattern)
    } else {
        const unsigned short* arow = e + rowbase + (size_t)(j0 + lane16)*128 + g*8;
        #pragma unroll
        for (int kst = 0; kst < 4; ++kst)
            a8[kst] = *(const short8v*)&arow[kst*32];
    }

    // --- GEMM1: e @ Wc + epilogue (D[j][n]: row=j0+g*4+r, col=nt*16+lane16)
    f32x4 tv[8];
    float agg[8];
    float s1[4] = {0,0,0,0}, q1[4] = {0,0,0,0};
    const int jb = j0 + g*4;
    float4 mk;
    if (DO_AGG) mk = *(const float4*)&adj[(size_t)b*393216 + (size_t)i*256 + jb];
    const float* mkp = (const float*)&mk;
    #pragma unroll
    for (int nt = 0; nt < 8; ++nt) {
        const int col = nt*16 + lane16;
        f32x4 acc = {0.f,0.f,0.f,0.f};
        #pragma unroll
        for (int kst = 0; kst < 4; ++kst) {
            short8v bfr = *(const short8v*)&WcF[((nt*4+kst) << 9) + (lane << 3)];
            acc = __builtin_amdgcn_mfma_f32_16x16x32_bf16(a8[kst], bfr, acc, 0, 0, 0);
        }
        const float bcB = bc_l[col] + Bh[bi*128 + col];
        if (DO_AGG) {
            float a = 0.f;
            #pragma unroll
            for (int r = 0; r < 4; ++r) {
                const float ahv = Ah[(size_t)(b*256 + jb + r)*128 + col];
                const float vhv = Vh[(size_t)(b*256 + jb + r)*128 + col];
                float tvl = acc[r] + bcB + ahv;
                a = fmaf(mkp[r]*sigmoidf_(tvl), vhv, a);
                s1[r] += tvl; q1[r] = fmaf(tvl, tvl, q1[r]);
                tv[nt][r] = tvl;
            }
            agg[nt] = a;
        } else {
            #pragma unroll
            for (int r = 0; r < 4; ++r) {
                const float ahv = Ah[(size_t)(b*256 + jb + r)*128 + col];
                float tvl = acc[r] + bcB + ahv;
                s1[r] += tvl; q1[r] = fmaf(tvl, tvl, q1[r]);
                tv[nt][r] = tvl;
            }
        }
    }
    // --- row stats 1 (wave-internal 16-lane reduce)
    float mu1[4], rs1[4];
    #pragma unroll
    for (int r = 0; r < 4; ++r) {
        float s = s1[r], q = q1[r];
        s += __shfl_xor(s,1); q += __shfl_xor(q,1);
        s += __shfl_xor(s,2); q += __shfl_xor(q,2);
        s += __shfl_xor(s,4); q += __shfl_xor(q,4);
        s += __shfl_xor(s,8); q += __shfl_xor(q,8);
        float mu = s*(1.f/128.f);
        mu1[r] = mu; rs1[r] = rsqrtf(q*(1.f/128.f) - mu*mu + EPSV);
    }
    // --- LN1 + relu, stats 2
    float s2[4] = {0,0,0,0}, q2[4] = {0,0,0,0};
    #pragma unroll
    for (int nt = 0; nt < 8; ++nt) {
        const int col = nt*16 + lane16;
        const float lg = lne_g[col], lb = lne_b[col];
        #pragma unroll
        for (int r = 0; r < 4; ++r) {
            float tp = fmaxf(fmaf((tv[nt][r]-mu1[r])*rs1[r], lg, lb), 0.f);
            tv[nt][r] = tp;
            s2[r] += tp; q2[r] = fmaf(tp, tp, q2[r]);
        }
    }
    float mu2[4], rs2[4];
    #pragma unroll
    for (int r = 0; r < 4; ++r) {
        float s = s2[r], q = q2[r];
        s += __shfl_xor(s,1); q += __shfl_xor(q,1);
        s += __shfl_xor(s,2); q += __shfl_xor(q,2);
        s += __shfl_xor(s,4); q += __shfl_xor(q,4);
        s += __shfl_xor(s,8); q += __shfl_xor(q,8);
        float mu = s*(1.f/128.f);
        mu2[r] = mu; rs2[r] = rsqrtf(q*(1.f/128.f) - mu*mu + EPSV);
    }

    // --- LN2 + silu -> Ua bf16 into wave-private slice (cvt_pk packing); same-wave DS ordering
    #pragma unroll
    for (int nt = 0; nt < 8; ++nt) {
        const int col = nt*16 + lane16;
        const float pg = plo_g[col], pb = plo_b[col];
        float u[4];
        #pragma unroll
        for (int r = 0; r < 4; ++r) {
            float uu = fmaf((tv[nt][r]-mu2[r])*rs2[r], pg, pb);
            u[r] = uu * sigmoidf_(uu);
        }
        const unsigned int p01 = cvtpk(u[0], u[1]);
        const unsigned int p23 = cvtpk(u[2], u[3]);
        const int r0 = g*4;
        *(unsigned short*)(sE + (r0+0)*256 + SWZ(r0+0, col*2)) = (unsigned short)p01;
        *(unsigned short*)(sE + (r0+1)*256 + SWZ(r0+1, col*2)) = (unsigned short)(p01 >> 16);
        *(unsigned short*)(sE + (r0+2)*256 + SWZ(r0+2, col*2)) = (unsigned short)p23;
        *(unsigned short*)(sE + (r0+3)*256 + SWZ(r0+3, col*2)) = (unsigned short)(p23 >> 16);
    }
    // --- B-frags for GEMM2 from own wave's Ua slice (same-wave DS ordering; no barrier)
    short8v b8[4];
    #pragma unroll
    for (int kst = 0; kst < 4; ++kst)
        b8[kst] = *(const short8v*)(sE + lane16*256 + SWZ(lane16, kst*64 + g*16));

    // --- GEMM2 (swapped): D'[n][j] = plo_W^T @ u^T. A-frag = PWF frag-ordered global.
    const int jg = j0 + lane16;   // this lane's output row
    float gs[8], gq[8];
    #pragma unroll
    for (int nt = 0; nt < 8; ++nt) {
        f32x4 acc = {0.f,0.f,0.f,0.f};
        #pragma unroll
        for (int kst = 0; kst < 4; ++kst) {
            short8v aw = *(const short8v*)&PWF[((nt*4+kst) << 9) + (lane << 3)];
            acc = __builtin_amdgcn_mfma_f32_16x16x32_bf16(aw, b8[kst], acc, 0, 0, 0);
        }
        const int n0 = nt*16 + g*4;
        const float4 pw4 = *(const float4*)&pbW_l[n0];
        const float* pwp = (const float*)&pw4;
        unsigned short* ep = &e[rowbase + (size_t)jg*128 + n0];
        const ushort4 ev = *(const ushort4*)ep;
        const float o0 = acc[0] + (pwp[0] + bf2f(ev.x));
        const float o1 = acc[1] + (pwp[1] + bf2f(ev.y));
        const float o2 = acc[2] + (pwp[2] + bf2f(ev.z));
        const float o3 = acc[3] + (pwp[3] + bf2f(ev.w));
        if (DO_STATS) {
            gs[nt] = (o0 + o1) + (o2 + o3);
            gq[nt] = fmaf(o0,o0, fmaf(o1,o1, fmaf(o2,o2, o3*o3)));
        }
        uint2 st;
        st.x = cvtpk(o0, o1);
        st.y = cvtpk(o2, o3);
        *(uint2*)ep = st;
    }

    // ---- block tail: agg reduce + atomic
    if (DO_AGG) {
        #pragma unroll
        for (int nt = 0; nt < 8; ++nt) {
            float a = agg[nt];
            a += __shfl_xor(a, 16); a += __shfl_xor(a, 32);
            if (lane < 16) sRedA[w*128 + nt*16 + lane] = a;
        }
        __syncthreads();
        if (t < 128) {
            float S = sRedA[t] + sRedA[128+t] + sRedA[256+t] + sRedA[384+t];
            atomicAdd(&aggB[bi*128 + t], S);
        }
    }
    // ---- block tail: GN group stats (group = nt*4+g; lane's 4 r-values same group)
    if (DO_STATS) {
        #pragma unroll
        for (int nt = 0; nt < 8; ++nt) {
            float a = gs[nt], qq = gq[nt];
            a += __shfl_xor(a, 1); qq += __shfl_xor(qq, 1);
            a += __shfl_xor(a, 2); qq += __shfl_xor(qq, 2);
            a += __shfl_xor(a, 4); qq += __shfl_xor(qq, 4);
            a += __shfl_xor(a, 8); qq += __shfl_xor(qq, 8);
            if (lane16 == 0) {
                sRedA[w*32 + nt*4 + g] = a;
                sRedB[w*32 + nt*4 + g] = qq;
            }
        }
        __syncthreads();
        if (t < 32) {
            float S = sRedA[t] + sRedA[32+t] + sRedA[64+t] + sRedA[96+t];
            float Q = sRedB[t] + sRedB[32+t] + sRedB[64+t] + sRedB[96+t];
            atomicAdd(&ggsum[b*32 + t], S);
            atomicAdd(&ggsq[b*32 + t], Q);
        }
    }
}

// ---------------- K7: finalize group stats (from group-level sums)
__global__ void k_gfin(const float* __restrict__ ggsum, const float* __restrict__ ggsq,
                       float* __restrict__ gmu, float* __restrict__ grs)
{
    int t = threadIdx.x; // 64 = b*32+g
    float s = ggsum[t], q = ggsq[t];
    const float invN = 1.f/(4.f*65536.f);
    float mu = s*invN;
    float var = q*invN - mu*mu;
    gmu[t] = mu;
    grs[t] = rsqrtf(var + EPSV);
}

// ---------------- K8: head: GN transform -> relu -> 1x1 conv (dot over 128 ch), bf16 e
__global__ __launch_bounds__(256) void k_head(
    const unsigned short* __restrict__ e, const float* __restrict__ gmu,
    const float* __restrict__ grs, const float* __restrict__ gn_g,
    const float* __restrict__ gn_b, const float* __restrict__ W_out,
    const float* __restrict__ b_out, float* __restrict__ out)
{
    const int blk = blockIdx.x, t = threadIdx.x;
    const int b = blk >> 8;
    const int ch8 = (t & 15)*8, jgrp = t >> 4;
    float gg[8], gb[8], wo[8];
    #pragma unroll
    for (int c = 0; c < 8; ++c) {
        const int ch = ch8 + c;
        const float mu = gmu[b*32 + (ch>>2)], rs = grs[b*32 + (ch>>2)];
        gg[c] = gn_g[ch]*rs;
        gb[c] = gn_b[ch] - mu*gg[c];
        wo[c] = W_out[ch];
    }
    const float bo = b_out[0];
    const unsigned short* erow = e + (size_t)blk*32768;
    float* orow = out + (size_t)blk*256;
    for (int it = 0; it < 16; ++it) {
        const int j = jgrp*16 + it;
        short8v v = *(const short8v*)&erow[(size_t)j*128 + ch8];
        float p = 0.f;
        #pragma unroll
        for (int c = 0; c < 8; ++c) {
            float f = bf2f((unsigned short)v[c]);
            p = fmaf(fmaxf(fmaf(f, gg[c], gb[c]), 0.f), wo[c], p);
        }
        p += __shfl_xor(p, 1); p += __shfl_xor(p, 2);
        p += __shfl_xor(p, 4); p += __shfl_xor(p, 8);
        if ((t & 15) == 0) orow[j] = p + bo;
    }
}

extern "C" void kernel_launch(void* const* d_in, const int* in_sizes, int n_in,
                              void* d_out, int out_size, void* d_ws, size_t ws_size,
                              hipStream_t stream)
{
    const int*   x      = (const int*)  d_in[0];
    const float* adj    = (const float*)d_in[1];
    const float* emb    = (const float*)d_in[2];
    const float* W_node = (const float*)d_in[3];
    const float* b_node = (const float*)d_in[4];
    const float* W_ea   = (const float*)d_in[5];
    const float* b_ea   = (const float*)d_in[6];
    const float* W_ee   = (const float*)d_in[7];
    const float* b_ee   = (const float*)d_in[8];
    const float* Wu     = (const float*)d_in[9];
    const float* bu     = (const float*)d_in[10];
    const float* Wv     = (const float*)d_in[11];
    const float* bv     = (const float*)d_in[12];
    const float* Wa     = (const float*)d_in[13];
    const float* ba     = (const float*)d_in[14];
    const float* Wb     = (const float*)d_in[15];
    const float* bb     = (const float*)d_in[16];
    const float* Wc     = (const float*)d_in[17];
    const float* bc     = (const float*)d_in[18];
    const float* lnh_g  = (const float*)d_in[19];
    const float* lnh_b  = (const float*)d_in[20];
    const float* lne_g  = (const float*)d_in[21];
    const float* lne_b  = (const float*)d_in[22];
    const float* plo_g  = (const float*)d_in[23];
    const float* plo_b  = (const float*)d_in[24];
    const float* plo_W  = (const float*)d_in[25];
    const float* plo_bW = (const float*)d_in[26];
    const float* gn_g   = (const float*)d_in[27];
    const float* gn_b   = (const float*)d_in[28];
    const float* W_out  = (const float*)d_in[29];
    const float* b_out  = (const float*)d_in[30];
    float* out = (float*)d_out;

    float* ws = (float*)d_ws;
    size_t off = 0;
    unsigned short* e = (unsigned short*)(ws + off); off += 8388608;  // 16.7M bf16 = 33.5 MB
    float* h    = ws + off; off += 65536;
    float* Uh   = ws + off; off += 65536;
    float* Bh   = ws + off; off += 65536;
    float* Vh   = ws + off; off += 65536;
    float* Ah   = ws + off; off += 65536;
    float* aggB = ws + off; off += 65536;
    float* Wcb  = ws + off; off += 768;
    float* bcb  = ws + off; off += 128;
    float* ggsum = ws + off; off += 64;
    float* ggsq  = ws + off; off += 64;   // contiguous with ggsum
    float* gmu  = ws + off; off += 64;
    float* grs  = ws + off; off += 64;
    unsigned short* WT = (unsigned short*)(ws + off); off += 49152;  // 6 x 128x128 bf16 (frag-ordered)

    k_prep<<<519, 256, 0, stream>>>(x, emb, W_node, b_node, h, aggB,
                                    W_ea, b_ea, W_ee, b_ee, Wcb, bcb,
                                    Wc, plo_W, WT);
    hipMemsetAsync(ggsum, 0, 512, stream);   // ggsum + ggsq

    for (int l = 0; l < 3; ++l) {
        k_hgemm<<<512, 128, 0, stream>>>(h, Uh, aggB,
            Wu + (size_t)l*16384, bu + l*128,
            Wv + (size_t)l*16384, bv + l*128,
            Wa + (size_t)l*16384, ba + l*128,
            Wb + (size_t)l*16384, bb + l*128,
            Vh, Ah, Bh,
            lnh_g + (l==0?0:(l-1)*128), lnh_b + (l==0?0:(l-1)*128), l > 0 ? 1 : 0);
        const unsigned short* WcF_l = WT + (size_t)(2*l)*16384;
        const unsigned short* PWF_l = WT + (size_t)(2*l+1)*16384;
        if (l == 0) {
            k_layer<1,1,0><<<2048, 256, 0, stream>>>(e, WcF_l, PWF_l,
                bc + l*128, Ah, Bh, Vh, adj,
                lne_g + l*128, lne_b + l*128,
                plo_g + l*128, plo_b + l*128,
                plo_bW + l*128, aggB, Wcb, bcb, ggsum, ggsq);
        } else if (l == 1) {
            k_layer<0,1,0><<<2048, 256, 0, stream>>>(e, WcF_l, PWF_l,
                bc + l*128, Ah, Bh, Vh, adj,
                lne_g + l*128, lne_b + l*128,
                plo_g + l*128, plo_b + l*128,
                plo_bW + l*128, aggB, Wcb, bcb, ggsum, ggsq);
        } else {
            k_layer<0,0,1><<<2048, 256, 0, stream>>>(e, WcF_l, PWF_l,
                bc + l*128, Ah, Bh, Vh, adj,
                lne_g + l*128, lne_b + l*128,
                plo_g + l*128, plo_b + l*128,
                plo_bW + l*128, aggB, Wcb, bcb, ggsum, ggsq);
        }
    }

    k_gfin<<<1, 64, 0, stream>>>(ggsum, ggsq, gmu, grs);
    k_head<<<512, 256, 0, stream>>>(e, gmu, grs, gn_g, gn_b, W_out, b_out, out);
}

// Round 18
// 212.391 us; speedup vs baseline: 1.2019x; 1.2019x over previous
//
#include <hip/hip_runtime.h>
#include <cstdint>
#include <cstddef>

// GNNDi: B=2, V=256, H=128, L=3, GroupNorm32 head. e stored [b][i][j][h] bf16.

#define EPSV 1e-5f

typedef __attribute__((ext_vector_type(8))) short short8v;  // 8 bf16
typedef __attribute__((ext_vector_type(4))) float f32x4;

__device__ __forceinline__ float sigmoidf_(float x) { return 1.f / (1.f + __expf(-x)); }

__device__ __forceinline__ unsigned short f2bf(float x) {
    unsigned int u = __float_as_uint(x);
    unsigned int r = u + 0x7FFFu + ((u >> 16) & 1u);   // RNE
    return (unsigned short)(r >> 16);
}
__device__ __forceinline__ float bf2f(unsigned short u) {
    return __uint_as_float(((unsigned int)u) << 16);
}
// packed f32x2 -> bf16x2 (RNE), lo=a, hi=b
__device__ __forceinline__ unsigned int cvtpk(float a, float b) {
    unsigned int r;
    asm("v_cvt_pk_bf16_f32 %0, %1, %2" : "=v"(r) : "v"(a), "v"(b));
    return r;
}
#define SWZ(row, cb) ((cb) ^ (((row) & 7) << 4))

// ---------------- K_prep: node embed + aggB zero (blocks 0..511), wcomb (512), weight transpose (513..518)
__global__ void k_prep(const int* __restrict__ x, const float* __restrict__ emb,
                       const float* __restrict__ W_node, const float* __restrict__ b_node,
                       float* __restrict__ h, float* __restrict__ aggB,
                       const float* __restrict__ W_ea, const float* __restrict__ b_ea,
                       const float* __restrict__ W_ee, const float* __restrict__ b_ee,
                       float* __restrict__ Wcb, float* __restrict__ bcb,
                       const float* __restrict__ Wc, const float* __restrict__ PW,
                       unsigned short* __restrict__ WT)
{
    const int blk = blockIdx.x, t = threadIdx.x;
    if (blk < 512) {
        __shared__ float se[128];
        if (t < 128) { se[t] = emb[x[blk]*128 + t]; aggB[blk*128 + t] = 0.f; }
        __syncthreads();
        if (t < 128) {
            float acc = b_node[t];
            for (int k = 0; k < 128; ++k) acc = fmaf(se[k], W_node[k*128+t], acc);
            h[blk*128+t] = acc;
        }
    } else if (blk == 512) {
        if (t < 128) {
            float wc0=0,wc1=0,wc2=0,wc3=0,wc4=0,wc5=0,bv=0;
            for (int m = 0; m < 128; ++m) {
                float we = W_ee[m*128 + t];
                wc0 = fmaf(W_ea[0*128+m], we, wc0);
                wc1 = fmaf(W_ea[1*128+m], we, wc1);
                wc2 = fmaf(W_ea[2*128+m], we, wc2);
                wc3 = fmaf(W_ea[3*128+m], we, wc3);
                wc4 = fmaf(W_ea[4*128+m], we, wc4);
                wc5 = fmaf(W_ea[5*128+m], we, wc5);
                bv  = fmaf(b_ea[m], we, bv);
            }
            Wcb[0*128+t]=wc0; Wcb[1*128+t]=wc1; Wcb[2*128+t]=wc2;
            Wcb[3*128+t]=wc3; Wcb[4*128+t]=wc4; Wcb[5*128+t]=wc5;
            bcb[t] = bv + b_ee[t];
        }
    } else {
        const int m = blk - 513;            // 0..5 = layer*2 + (0:Wc, 1:plo_W)
        const int l = m >> 1;
        const float* src = (m & 1) ? (PW + (size_t)l*16384) : (Wc + (size_t)l*16384);
        unsigned short* dst = WT + (size_t)m*16384;
        for (int idx = t; idx < 16384; idx += 256) {
            int n = idx >> 7, k = idx & 127;
            dst[idx] = f2bf(src[k*128 + n]);   // [n][k] bf16 (transposed)
        }
    }
}

// ---------------- K3: fused h-update (from prev layer) + 4 h-GEMMs; zeroes aggB
// All outputs non-transposed [b*256+v][128].
__global__ void k_hgemm(float* __restrict__ h, float* __restrict__ Uh, float* __restrict__ aggB,
    const float* __restrict__ Wu_l, const float* __restrict__ bu_l,
    const float* __restrict__ Wv_l, const float* __restrict__ bv_l,
    const float* __restrict__ Wa_l, const float* __restrict__ ba_l,
    const float* __restrict__ Wb_l, const float* __restrict__ bb_l,
    float* __restrict__ Vh, float* __restrict__ Ah, float* __restrict__ Bh,
    const float* __restrict__ lnh_g, const float* __restrict__ lnh_b, int upd)
{
    __shared__ float sh[128];
    __shared__ float sred[4];
    int blk = blockIdx.x, t = threadIdx.x;
    float hv_ = h[blk*128 + t];
    if (upd) {
        float val = Uh[blk*128 + t] + aggB[blk*128 + t];
        aggB[blk*128 + t] = 0.f;
        float s = val, q = val*val;
        #pragma unroll
        for (int off = 32; off; off >>= 1) { s += __shfl_down(s, off); q += __shfl_down(q, off); }
        if ((t & 63) == 0) { sred[t>>6] = s; sred[2 + (t>>6)] = q; }
        __syncthreads();
        s = sred[0] + sred[1]; q = sred[2] + sred[3];
        float mean = s * (1.f/128.f);
        float var  = q * (1.f/128.f) - mean*mean;
        float nv = (val - mean) * rsqrtf(var + EPSV) * lnh_g[t] + lnh_b[t];
        hv_ += fmaxf(nv, 0.f);
        h[blk*128 + t] = hv_;
    }
    sh[t] = hv_;
    __syncthreads();
    float au=bu_l[t], av=bv_l[t], aa=ba_l[t], ab=bb_l[t];
    for (int k = 0; k < 128; ++k) {
        float hv = sh[k];
        au = fmaf(hv, Wu_l[k*128+t], au);
        av = fmaf(hv, Wv_l[k*128+t], av);
        aa = fmaf(hv, Wa_l[k*128+t], aa);
        ab = fmaf(hv, Wb_l[k*128+t], ab);
    }
    Uh[blk*128+t]=au; Bh[blk*128+t]=ab;
    Vh[blk*128+t]=av; Ah[blk*128+t]=aa;
}

// ---------------- K4: fused layer chunk. grid = 2048; 256 threads; each wave owns 16 rows x 128 cols.
// EINIT: layer-1 computes e0 on the fly, stores it to e, residual read back in epilogue.
// DO_STATS: layer-3 accumulates GroupNorm group-level sums (group = ch>>2 = nt*4+g).
template<int EINIT, int DO_AGG, int DO_STATS>
__global__ __launch_bounds__(256) void k_layer(
    unsigned short* __restrict__ e,
    const unsigned short* __restrict__ WcT, const unsigned short* __restrict__ PWT,
    const float* __restrict__ bc_l,
    const float* __restrict__ Ah, const float* __restrict__ Bh,
    const float* __restrict__ Vh, const float* __restrict__ adj,
    const float* __restrict__ lne_g, const float* __restrict__ lne_b,
    const float* __restrict__ plo_g, const float* __restrict__ plo_b,
    const float* __restrict__ pbW_l,
    float* __restrict__ aggB,
    const float* __restrict__ Wcb, const float* __restrict__ bcb,
    float* __restrict__ ggsum, float* __restrict__ ggsq)
{
    __shared__ __align__(16) char sW[32768];     // weight matrix bf16, swizzled; Ua overlays per-wave
    __shared__ float sRedA[512];
    __shared__ float sRedB[128];

    const int t = threadIdx.x;
    const int bi = blockIdx.x >> 2, chunk = blockIdx.x & 3;
    const int b = bi >> 8, i = bi & 255;
    const int w = t >> 6, lane = t & 63;
    const int lane16 = lane & 15, g = lane >> 4;
    const size_t rowbase = (size_t)bi * 32768;
    const int j0 = chunk*64 + w*16;
    char* sE = sW + w*4096;      // wave-private 4KB slice (valid only between barriers 2 and 3)

    // --- GEMM1 A-frags
    short8v a8[4];
    if (EINIT) {
        float am[6];
        const float* adjp = adj + (size_t)b*393216 + (size_t)i*256 + (j0 + lane16);
        #pragma unroll
        for (int m = 0; m < 6; ++m) am[m] = adjp[(size_t)m*65536];
        unsigned short* erow = &e[rowbase + (size_t)(j0 + lane16)*128];
        #pragma unroll
        for (int kst = 0; kst < 4; ++kst) {
            const int base = kst*32 + g*8;
            float4 v0 = *(const float4*)&bcb[base];
            float4 v1 = *(const float4*)&bcb[base+4];
            float vv[8] = {v0.x, v0.y, v0.z, v0.w, v1.x, v1.y, v1.z, v1.w};
            #pragma unroll
            for (int m = 0; m < 6; ++m) {
                const float4 w0 = *(const float4*)&Wcb[m*128 + base];
                const float4 w1 = *(const float4*)&Wcb[m*128 + base + 4];
                vv[0] = fmaf(am[m], w0.x, vv[0]); vv[1] = fmaf(am[m], w0.y, vv[1]);
                vv[2] = fmaf(am[m], w0.z, vv[2]); vv[3] = fmaf(am[m], w0.w, vv[3]);
                vv[4] = fmaf(am[m], w1.x, vv[4]); vv[5] = fmaf(am[m], w1.y, vv[5]);
                vv[6] = fmaf(am[m], w1.z, vv[6]); vv[7] = fmaf(am[m], w1.w, vv[7]);
            }
            short8v vfr;
            #pragma unroll
            for (int pr = 0; pr < 4; ++pr) {
                const unsigned int p = cvtpk(vv[pr*2], vv[pr*2+1]);
                vfr[pr*2]   = (short)(unsigned short)p;
                vfr[pr*2+1] = (short)(unsigned short)(p >> 16);
            }
            a8[kst] = vfr;
            *(short8v*)&erow[base] = vfr;   // materialize e0 (residual readback in epilogue)
        }
    } else {
        const unsigned short* arow = e + rowbase + (size_t)(j0 + lane16)*128 + g*8;
        #pragma unroll
        for (int kst = 0; kst < 4; ++kst)
            a8[kst] = *(const short8v*)&arow[kst*32];
    }

    // --- stage Wc into LDS (dense global reads, swizzled LDS writes)
    #pragma unroll
    for (int p = 0; p < 8; ++p) {
        const int idx = t*8 + p*2048;            // short index
        const int n = idx >> 7, cb = (idx & 127) << 1;
        *(short8v*)(sW + n*256 + SWZ(n, cb)) = *(const short8v*)&WcT[idx];
    }
    __syncthreads();   // (1) Wc staged; EINIT e0 stores drained

    // --- GEMM1: e @ Wc + epilogue (D[j][n]: row=j0+g*4+r, col=nt*16+lane16)
    f32x4 tv[8];
    float agg[8];
    float s1[4] = {0,0,0,0}, q1[4] = {0,0,0,0};
    const int jb = j0 + g*4;
    float4 mk;
    if (DO_AGG) mk = *(const float4*)&adj[(size_t)b*393216 + (size_t)i*256 + jb];
    const float* mkp = (const float*)&mk;
    #pragma unroll
    for (int nt = 0; nt < 8; ++nt) {
        const int col = nt*16 + lane16;
        f32x4 acc = {0.f,0.f,0.f,0.f};
        #pragma unroll
        for (int kst = 0; kst < 4; ++kst) {
            short8v bfr = *(const short8v*)(sW + col*256 + SWZ(col, kst*64 + g*16));
            acc = __builtin_amdgcn_mfma_f32_16x16x32_bf16(a8[kst], bfr, acc, 0, 0, 0);
        }
        const float bcB = bc_l[col] + Bh[bi*128 + col];
        if (DO_AGG) {
            float a = 0.f;
            #pragma unroll
            for (int r = 0; r < 4; ++r) {
                const float ahv = Ah[(size_t)(b*256 + jb + r)*128 + col];
                const float vhv = Vh[(size_t)(b*256 + jb + r)*128 + col];
                float tvl = acc[r] + bcB + ahv;
                a = fmaf(mkp[r]*sigmoidf_(tvl), vhv, a);
                s1[r] += tvl; q1[r] = fmaf(tvl, tvl, q1[r]);
                tv[nt][r] = tvl;
            }
            agg[nt] = a;
        } else {
            #pragma unroll
            for (int r = 0; r < 4; ++r) {
                const float ahv = Ah[(size_t)(b*256 + jb + r)*128 + col];
                float tvl = acc[r] + bcB + ahv;
                s1[r] += tvl; q1[r] = fmaf(tvl, tvl, q1[r]);
                tv[nt][r] = tvl;
            }
        }
    }
    // --- row stats 1 (wave-internal 16-lane reduce)
    float mu1[4], rs1[4];
    #pragma unroll
    for (int r = 0; r < 4; ++r) {
        float s = s1[r], q = q1[r];
        s += __shfl_xor(s,1); q += __shfl_xor(q,1);
        s += __shfl_xor(s,2); q += __shfl_xor(q,2);
        s += __shfl_xor(s,4); q += __shfl_xor(q,4);
        s += __shfl_xor(s,8); q += __shfl_xor(q,8);
        float mu = s*(1.f/128.f);
        mu1[r] = mu; rs1[r] = rsqrtf(q*(1.f/128.f) - mu*mu + EPSV);
    }
    // --- LN1 + relu, stats 2
    float s2[4] = {0,0,0,0}, q2[4] = {0,0,0,0};
    #pragma unroll
    for (int nt = 0; nt < 8; ++nt) {
        const int col = nt*16 + lane16;
        const float lg = lne_g[col], lb = lne_b[col];
        #pragma unroll
        for (int r = 0; r < 4; ++r) {
            float tp = fmaxf(fmaf((tv[nt][r]-mu1[r])*rs1[r], lg, lb), 0.f);
            tv[nt][r] = tp;
            s2[r] += tp; q2[r] = fmaf(tp, tp, q2[r]);
        }
    }
    float mu2[4], rs2[4];
    #pragma unroll
    for (int r = 0; r < 4; ++r) {
        float s = s2[r], q = q2[r];
        s += __shfl_xor(s,1); q += __shfl_xor(q,1);
        s += __shfl_xor(s,2); q += __shfl_xor(q,2);
        s += __shfl_xor(s,4); q += __shfl_xor(q,4);
        s += __shfl_xor(s,8); q += __shfl_xor(q,8);
        float mu = s*(1.f/128.f);
        mu2[r] = mu; rs2[r] = rsqrtf(q*(1.f/128.f) - mu*mu + EPSV);
    }

    __syncthreads();   // (2) all waves done reading Wc; sW slices now free for Ua

    // --- LN2 + silu -> Ua bf16 into wave-private slice (cvt_pk packing)
    #pragma unroll
    for (int nt = 0; nt < 8; ++nt) {
        const int col = nt*16 + lane16;
        const float pg = plo_g[col], pb = plo_b[col];
        float u[4];
        #pragma unroll
        for (int r = 0; r < 4; ++r) {
            float uu = fmaf((tv[nt][r]-mu2[r])*rs2[r], pg, pb);
            u[r] = uu * sigmoidf_(uu);
        }
        const unsigned int p01 = cvtpk(u[0], u[1]);
        const unsigned int p23 = cvtpk(u[2], u[3]);
        const int r0 = g*4;
        *(unsigned short*)(sE + (r0+0)*256 + SWZ(r0+0, col*2)) = (unsigned short)p01;
        *(unsigned short*)(sE + (r0+1)*256 + SWZ(r0+1, col*2)) = (unsigned short)(p01 >> 16);
        *(unsigned short*)(sE + (r0+2)*256 + SWZ(r0+2, col*2)) = (unsigned short)p23;
        *(unsigned short*)(sE + (r0+3)*256 + SWZ(r0+3, col*2)) = (unsigned short)(p23 >> 16);
    }
    // --- B-frags for GEMM2 from own wave's Ua slice (same-wave DS ordering)
    short8v b8[4];
    #pragma unroll
    for (int kst = 0; kst < 4; ++kst)
        b8[kst] = *(const short8v*)(sE + lane16*256 + SWZ(lane16, kst*64 + g*16));

    __syncthreads();   // (3) Ua consumed; sW free for PWT
    // --- stage PWT into LDS
    #pragma unroll
    for (int p = 0; p < 8; ++p) {
        const int idx = t*8 + p*2048;
        const int n = idx >> 7, cb = (idx & 127) << 1;
        *(short8v*)(sW + n*256 + SWZ(n, cb)) = *(const short8v*)&PWT[idx];
    }
    __syncthreads();   // (4) PWT staged

    // --- GEMM2 (swapped): D'[n][j] = plo_W^T @ u^T. A-frag = PWT rows from LDS.
    const int jg = j0 + lane16;   // this lane's output row
    float gs[8], gq[8];
    #pragma unroll
    for (int nt = 0; nt < 8; ++nt) {
        const int an = nt*16 + lane16;
        f32x4 acc = {0.f,0.f,0.f,0.f};
        #pragma unroll
        for (int kst = 0; kst < 4; ++kst) {
            short8v aw = *(const short8v*)(sW + an*256 + SWZ(an, kst*64 + g*16));
            acc = __builtin_amdgcn_mfma_f32_16x16x32_bf16(aw, b8[kst], acc, 0, 0, 0);
        }
        const int n0 = nt*16 + g*4;
        const float4 pw4 = *(const float4*)&pbW_l[n0];
        const float* pwp = (const float*)&pw4;
        unsigned short* ep = &e[rowbase + (size_t)jg*128 + n0];
        const ushort4 ev = *(const ushort4*)ep;
        const float o0 = acc[0] + (pwp[0] + bf2f(ev.x));
        const float o1 = acc[1] + (pwp[1] + bf2f(ev.y));
        const float o2 = acc[2] + (pwp[2] + bf2f(ev.z));
        const float o3 = acc[3] + (pwp[3] + bf2f(ev.w));
        if (DO_STATS) {
            gs[nt] = (o0 + o1) + (o2 + o3);
            gq[nt] = fmaf(o0,o0, fmaf(o1,o1, fmaf(o2,o2, o3*o3)));
        }
        uint2 st;
        st.x = cvtpk(o0, o1);
        st.y = cvtpk(o2, o3);
        *(uint2*)ep = st;
    }

    // ---- block tail: agg reduce + atomic
    if (DO_AGG) {
        #pragma unroll
        for (int nt = 0; nt < 8; ++nt) {
            float a = agg[nt];
            a += __shfl_xor(a, 16); a += __shfl_xor(a, 32);
            if (lane < 16) sRedA[w*128 + nt*16 + lane] = a;
        }
        __syncthreads();
        if (t < 128) {
            float S = sRedA[t] + sRedA[128+t] + sRedA[256+t] + sRedA[384+t];
            atomicAdd(&aggB[bi*128 + t], S);
        }
    }
    // ---- block tail: GN group stats (group = nt*4+g; lane's 4 r-values same group)
    if (DO_STATS) {
        #pragma unroll
        for (int nt = 0; nt < 8; ++nt) {
            float a = gs[nt], qq = gq[nt];
            a += __shfl_xor(a, 1); qq += __shfl_xor(qq, 1);
            a += __shfl_xor(a, 2); qq += __shfl_xor(qq, 2);
            a += __shfl_xor(a, 4); qq += __shfl_xor(qq, 4);
            a += __shfl_xor(a, 8); qq += __shfl_xor(qq, 8);
            if (lane16 == 0) {
                sRedA[w*32 + nt*4 + g] = a;
                sRedB[w*32 + nt*4 + g] = qq;
            }
        }
        __syncthreads();
        if (t < 32) {
            float S = sRedA[t] + sRedA[32+t] + sRedA[64+t] + sRedA[96+t];
            float Q = sRedB[t] + sRedB[32+t] + sRedB[64+t] + sRedB[96+t];
            atomicAdd(&ggsum[b*32 + t], S);
            atomicAdd(&ggsq[b*32 + t], Q);
        }
    }
}

// ---------------- K7: finalize group stats (from group-level sums)
__global__ void k_gfin(const float* __restrict__ ggsum, const float* __restrict__ ggsq,
                       float* __restrict__ gmu, float* __restrict__ grs)
{
    int t = threadIdx.x; // 64 = b*32+g
    float s = ggsum[t], q = ggsq[t];
    const float invN = 1.f/(4.f*65536.f);
    float mu = s*invN;
    float var = q*invN - mu*mu;
    gmu[t] = mu;
    grs[t] = rsqrtf(var + EPSV);
}

// ---------------- K8: head: GN transform -> relu -> 1x1 conv (dot over 128 ch), bf16 e
__global__ __launch_bounds__(256) void k_head(
    const unsigned short* __restrict__ e, const float* __restrict__ gmu,
    const float* __restrict__ grs, const float* __restrict__ gn_g,
    const float* __restrict__ gn_b, const float* __restrict__ W_out,
    const float* __restrict__ b_out, float* __restrict__ out)
{
    const int blk = blockIdx.x, t = threadIdx.x;
    const int b = blk >> 8;
    const int ch8 = (t & 15)*8, jgrp = t >> 4;
    float gg[8], gb[8], wo[8];
    #pragma unroll
    for (int c = 0; c < 8; ++c) {
        const int ch = ch8 + c;
        const float mu = gmu[b*32 + (ch>>2)], rs = grs[b*32 + (ch>>2)];
        gg[c] = gn_g[ch]*rs;
        gb[c] = gn_b[ch] - mu*gg[c];
        wo[c] = W_out[ch];
    }
    const float bo = b_out[0];
    const unsigned short* erow = e + (size_t)blk*32768;
    float* orow = out + (size_t)blk*256;
    for (int it = 0; it < 16; ++it) {
        const int j = jgrp*16 + it;
        short8v v = *(const short8v*)&erow[(size_t)j*128 + ch8];
        float p = 0.f;
        #pragma unroll
        for (int c = 0; c < 8; ++c) {
            float f = bf2f((unsigned short)v[c]);
            p = fmaf(fmaxf(fmaf(f, gg[c], gb[c]), 0.f), wo[c], p);
        }
        p += __shfl_xor(p, 1); p += __shfl_xor(p, 2);
        p += __shfl_xor(p, 4); p += __shfl_xor(p, 8);
        if ((t & 15) == 0) orow[j] = p + bo;
    }
}

extern "C" void kernel_launch(void* const* d_in, const int* in_sizes, int n_in,
                              void* d_out, int out_size, void* d_ws, size_t ws_size,
                              hipStream_t stream)
{
    const int*   x      = (const int*)  d_in[0];
    const float* adj    = (const float*)d_in[1];
    const float* emb    = (const float*)d_in[2];
    const float* W_node = (const float*)d_in[3];
    const float* b_node = (const float*)d_in[4];
    const float* W_ea   = (const float*)d_in[5];
    const float* b_ea   = (const float*)d_in[6];
    const float* W_ee   = (const float*)d_in[7];
    const float* b_ee   = (const float*)d_in[8];
    const float* Wu     = (const float*)d_in[9];
    const float* bu     = (const float*)d_in[10];
    const float* Wv     = (const float*)d_in[11];
    const float* bv     = (const float*)d_in[12];
    const float* Wa     = (const float*)d_in[13];
    const float* ba     = (const float*)d_in[14];
    const float* Wb     = (const float*)d_in[15];
    const float* bb     = (const float*)d_in[16];
    const float* Wc     = (const float*)d_in[17];
    const float* bc     = (const float*)d_in[18];
    const float* lnh_g  = (const float*)d_in[19];
    const float* lnh_b  = (const float*)d_in[20];
    const float* lne_g  = (const float*)d_in[21];
    const float* lne_b  = (const float*)d_in[22];
    const float* plo_g  = (const float*)d_in[23];
    const float* plo_b  = (const float*)d_in[24];
    const float* plo_W  = (const float*)d_in[25];
    const float* plo_bW = (const float*)d_in[26];
    const float* gn_g   = (const float*)d_in[27];
    const float* gn_b   = (const float*)d_in[28];
    const float* W_out  = (const float*)d_in[29];
    const float* b_out  = (const float*)d_in[30];
    float* out = (float*)d_out;

    float* ws = (float*)d_ws;
    size_t off = 0;
    unsigned short* e = (unsigned short*)(ws + off); off += 8388608;  // 16.7M bf16 = 33.5 MB
    float* h    = ws + off; off += 65536;
    float* Uh   = ws + off; off += 65536;
    float* Bh   = ws + off; off += 65536;
    float* Vh   = ws + off; off += 65536;
    float* Ah   = ws + off; off += 65536;
    float* aggB = ws + off; off += 65536;
    float* Wcb  = ws + off; off += 768;
    float* bcb  = ws + off; off += 128;
    float* ggsum = ws + off; off += 64;
    float* ggsq  = ws + off; off += 64;   // contiguous with ggsum
    float* gmu  = ws + off; off += 64;
    float* grs  = ws + off; off += 64;
    unsigned short* WT = (unsigned short*)(ws + off); off += 49152;  // 6 x 128x128 bf16

    k_prep<<<519, 256, 0, stream>>>(x, emb, W_node, b_node, h, aggB,
                                    W_ea, b_ea, W_ee, b_ee, Wcb, bcb,
                                    Wc, plo_W, WT);
    hipMemsetAsync(ggsum, 0, 512, stream);   // ggsum + ggsq

    for (int l = 0; l < 3; ++l) {
        k_hgemm<<<512, 128, 0, stream>>>(h, Uh, aggB,
            Wu + (size_t)l*16384, bu + l*128,
            Wv + (size_t)l*16384, bv + l*128,
            Wa + (size_t)l*16384, ba + l*128,
            Wb + (size_t)l*16384, bb + l*128,
            Vh, Ah, Bh,
            lnh_g + (l==0?0:(l-1)*128), lnh_b + (l==0?0:(l-1)*128), l > 0 ? 1 : 0);
        const unsigned short* WcT_l = WT + (size_t)(2*l)*16384;
        const unsigned short* PWT_l = WT + (size_t)(2*l+1)*16384;
        if (l == 0) {
            k_layer<1,1,0><<<2048, 256, 0, stream>>>(e, WcT_l, PWT_l,
                bc + l*128, Ah, Bh, Vh, adj,
                lne_g + l*128, lne_b + l*128,
                plo_g + l*128, plo_b + l*128,
                plo_bW + l*128, aggB, Wcb, bcb, ggsum, ggsq);
        } else if (l == 1) {
            k_layer<0,1,0><<<2048, 256, 0, stream>>>(e, WcT_l, PWT_l,
                bc + l*128, Ah, Bh, Vh, adj,
                lne_g + l*128, lne_b + l*128,
                plo_g + l*128, plo_b + l*128,
                plo_bW + l*128, aggB, Wcb, bcb, ggsum, ggsq);
        } else {
            k_layer<0,0,1><<<2048, 256, 0, stream>>>(e, WcT_l, PWT_l,
                bc + l*128, Ah, Bh, Vh, adj,
                lne_g + l*128, lne_b + l*128,
                plo_g + l*128, plo_b + l*128,
                plo_bW + l*128, aggB, Wcb, bcb, ggsum, ggsq);
        }
    }

    k_gfin<<<1, 64, 0, stream>>>(ggsum, ggsq, gmu, grs);
    k_head<<<512, 256, 0, stream>>>(e, gmu, grs, gn_g, gn_b, W_out, b_out, out);
}